// Round 8
// baseline (360.350 us; speedup 1.0000x reference)
//
#include <hip/hip_runtime.h>
#include <hip/hip_fp16.h>

// Integration_block: scaling-and-squaring SVF integration.
// flow = SVF * 2^-7; 7x: flow = flow + trilerp(flow, p + flow), zeros padding.
// Shape (1, 3, 160, 192, 224) fp32 planar in/out.
//
// Intermediates: fp16 xyz-tight-interleaved (6 B/voxel). Each thread handles
// a PAIR of w-adjacent voxels: own-load = one aligned 12 B dwordx3, 8
// 16 B covering gather windows in flight (2x MLP vs 1 voxel/thread), and the
// store is one aligned 12 B dwordx3 (no sub-dword stores). Covering loads
// handle the 6 B granularity: read the 4B-aligned 16 B window, funnel-shift
// by half-parity.

#define D_ 160
#define H_ 192
#define W_ 224
static constexpr int NV = D_ * H_ * W_;   // 6,881,280
static constexpr int NP = NV / 2;         // voxel pairs
static constexpr float S_ = 0.0078125f;   // 2^-7
typedef unsigned int u32;

struct __attribute__((packed, aligned(4))) U4 { u32 a, b, c, d; };
struct __attribute__((packed, aligned(4))) U3 { u32 a, b, c; };

__device__ __forceinline__ float2 h2f(u32 h) {
    __half2 x = *(__half2*)&h;
    return __half22float2(x);
}
__device__ __forceinline__ u32 pk(float a, float b) {
    __half2 h = __floats2half2_rn(a, b);
    return *(u32*)&h;
}

// planar fp32 SVF -> tight fp16 interleaved, scale folded. 4 voxels/thread.
__global__ __launch_bounds__(256) void scale_k(const float* __restrict__ svf,
                                               u32* __restrict__ out) {
    const int i = blockIdx.x * 256 + threadIdx.x;   // NV/4 ids
    float4 a = ((const float4*)svf)[i];
    float4 b = ((const float4*)(svf + NV))[i];
    float4 c = ((const float4*)(svf + 2 * NV))[i];
    u32* o = out + 6 * (size_t)i;
    o[0] = pk(a.x * S_, b.x * S_);
    o[1] = pk(c.x * S_, a.y * S_);
    o[2] = pk(b.y * S_, c.y * S_);
    o[3] = pk(a.z * S_, b.z * S_);
    o[4] = pk(c.z * S_, a.w * S_);
    o[5] = pk(b.w * S_, c.w * S_);
}

// Extract two voxels' xyz (6 halves) from a 16B window with half-parity s.
__device__ __forceinline__ void extract6(const U4& u, int s, float2& p0,
                                         float2& p1, float2& p2) {
    const u32 v0 = s ? ((u.a >> 16) | (u.b << 16)) : u.a;
    const u32 v1 = s ? ((u.b >> 16) | (u.c << 16)) : u.b;
    const u32 v2 = s ? ((u.c >> 16) | (u.d << 16)) : u.c;
    p0 = h2f(v0);   // x0 y0
    p1 = h2f(v1);   // z0 x1
    p2 = h2f(v2);   // y1 z1
}

template <int PLANAR_OUT>
__global__ __launch_bounds__(448) void compose_k(const u32* __restrict__ in,
                                                 void* __restrict__ out_) {
    const int wp = blockIdx.x * 56 + threadIdx.x;  // pair index in row: 112/56=2
    const int h  = blockIdx.y * 8 + threadIdx.y;   // 192/8 = 24
    const int d  = blockIdx.z;                     // 160
    const int pairIdx = (d * H_ + h) * 112 + wp;

    // own pair: 12B aligned dwordx3
    const U3 uo = *(const U3*)(in + 3 * (size_t)pairIdx);
    const float2 A01 = h2f(uo.a);   // fA0 fA1
    const float2 M   = h2f(uo.b);   // fA2 fB0
    const float2 B12 = h2f(uo.c);   // fB1 fB2

    const int wA = 2 * wp, wB = 2 * wp + 1;

    // voxel A sample position
    const float pdA = (float)d + A01.x;
    const float phA = (float)h + A01.y;
    const float pwA = (float)wA + M.x;
    // voxel B
    const float pdB = (float)d + M.y;
    const float phB = (float)h + B12.x;
    const float pwB = (float)wB + B12.y;

    const float dAf = floorf(pdA), hAf = floorf(phA), wAf = floorf(pwA);
    const float dBf = floorf(pdB), hBf = floorf(phB), wBf = floorf(pwB);
    const int d0A = (int)dAf, h0A = (int)hAf, w0A = (int)wAf;
    const int d0B = (int)dBf, h0B = (int)hBf, w0B = (int)wBf;
    const float fdA = pdA - dAf, fhA = phA - hAf, fwA = pwA - wAf;
    const float fdB = pdB - dBf, fhB = phB - hBf, fwB = pwB - wBf;

    float aA0, aA1, aA2, aB0, aB1, aB2;

    const bool intA = ((unsigned)d0A <= (unsigned)(D_ - 2)) &
                      ((unsigned)h0A <= (unsigned)(H_ - 2)) &
                      ((unsigned)w0A <= (unsigned)(W_ - 2));
    const bool intB = ((unsigned)d0B <= (unsigned)(D_ - 2)) &
                      ((unsigned)h0B <= (unsigned)(H_ - 2)) &
                      ((unsigned)w0B <= (unsigned)(W_ - 2));

    if (intA & intB) {
        const int jA = (d0A * H_ + h0A) * W_ + w0A;
        const int jB = (d0B * H_ + h0B) * W_ + w0B;
        const int HA0 = 3 * jA, HA1 = 3 * (jA + W_);
        const int HA2 = 3 * (jA + H_ * W_), HA3 = 3 * (jA + H_ * W_ + W_);
        const int HB0 = 3 * jB, HB1 = 3 * (jB + W_);
        const int HB2 = 3 * (jB + H_ * W_), HB3 = 3 * (jB + H_ * W_ + W_);

        // all 8 covering loads issued before any consumption
        const U4 uA0 = *(const U4*)(in + (HA0 >> 1));
        const U4 uA1 = *(const U4*)(in + (HA1 >> 1));
        const U4 uA2 = *(const U4*)(in + (HA2 >> 1));
        const U4 uA3 = *(const U4*)(in + (HA3 >> 1));
        const U4 uB0 = *(const U4*)(in + (HB0 >> 1));
        const U4 uB1 = *(const U4*)(in + (HB1 >> 1));
        const U4 uB2 = *(const U4*)(in + (HB2 >> 1));
        const U4 uB3 = *(const U4*)(in + (HB3 >> 1));

        {
            const float ww1 = fwA, ww0 = 1.f - fwA;
            const float wh1 = fhA, wh0 = 1.f - fhA;
            const float wd1 = fdA, wd0 = 1.f - fdA;
            const float c00 = wd0 * wh0, c01 = wd0 * wh1;
            const float c10 = wd1 * wh0, c11 = wd1 * wh1;
            float2 p0, p1, p2;
            aA0 = aA1 = aA2 = 0.f;
            extract6(uA0, HA0 & 1, p0, p1, p2);
            aA0 += c00 * (ww0 * p0.x + ww1 * p1.y);
            aA1 += c00 * (ww0 * p0.y + ww1 * p2.x);
            aA2 += c00 * (ww0 * p1.x + ww1 * p2.y);
            extract6(uA1, HA1 & 1, p0, p1, p2);
            aA0 += c01 * (ww0 * p0.x + ww1 * p1.y);
            aA1 += c01 * (ww0 * p0.y + ww1 * p2.x);
            aA2 += c01 * (ww0 * p1.x + ww1 * p2.y);
            extract6(uA2, HA2 & 1, p0, p1, p2);
            aA0 += c10 * (ww0 * p0.x + ww1 * p1.y);
            aA1 += c10 * (ww0 * p0.y + ww1 * p2.x);
            aA2 += c10 * (ww0 * p1.x + ww1 * p2.y);
            extract6(uA3, HA3 & 1, p0, p1, p2);
            aA0 += c11 * (ww0 * p0.x + ww1 * p1.y);
            aA1 += c11 * (ww0 * p0.y + ww1 * p2.x);
            aA2 += c11 * (ww0 * p1.x + ww1 * p2.y);
        }
        {
            const float ww1 = fwB, ww0 = 1.f - fwB;
            const float wh1 = fhB, wh0 = 1.f - fhB;
            const float wd1 = fdB, wd0 = 1.f - fdB;
            const float c00 = wd0 * wh0, c01 = wd0 * wh1;
            const float c10 = wd1 * wh0, c11 = wd1 * wh1;
            float2 p0, p1, p2;
            aB0 = aB1 = aB2 = 0.f;
            extract6(uB0, HB0 & 1, p0, p1, p2);
            aB0 += c00 * (ww0 * p0.x + ww1 * p1.y);
            aB1 += c00 * (ww0 * p0.y + ww1 * p2.x);
            aB2 += c00 * (ww0 * p1.x + ww1 * p2.y);
            extract6(uB1, HB1 & 1, p0, p1, p2);
            aB0 += c01 * (ww0 * p0.x + ww1 * p1.y);
            aB1 += c01 * (ww0 * p0.y + ww1 * p2.x);
            aB2 += c01 * (ww0 * p1.x + ww1 * p2.y);
            extract6(uB2, HB2 & 1, p0, p1, p2);
            aB0 += c10 * (ww0 * p0.x + ww1 * p1.y);
            aB1 += c10 * (ww0 * p0.y + ww1 * p2.x);
            aB2 += c10 * (ww0 * p1.x + ww1 * p2.y);
            extract6(uB3, HB3 & 1, p0, p1, p2);
            aB0 += c11 * (ww0 * p0.x + ww1 * p1.y);
            aB1 += c11 * (ww0 * p0.y + ww1 * p2.x);
            aB2 += c11 * (ww0 * p1.x + ww1 * p2.y);
        }
    } else {
        // boundary: per-corner bounds-checked scalar-half gather (zeros pad)
        const __half* hp = (const __half*)in;
        float acc[2][3];
        const int d0_[2] = {d0A, d0B}, h0_[2] = {h0A, h0B}, w0_[2] = {w0A, w0B};
        const float fd_[2] = {fdA, fdB}, fh_[2] = {fhA, fhB}, fw_[2] = {fwA, fwB};
#pragma unroll
        for (int v = 0; v < 2; ++v) {
            acc[v][0] = acc[v][1] = acc[v][2] = 0.f;
#pragma unroll
            for (int dz = 0; dz < 2; ++dz) {
                const int cd = d0_[v] + dz;
                if ((unsigned)cd >= (unsigned)D_) continue;
                const float wz = dz ? fd_[v] : (1.f - fd_[v]);
#pragma unroll
                for (int dy = 0; dy < 2; ++dy) {
                    const int ch = h0_[v] + dy;
                    if ((unsigned)ch >= (unsigned)H_) continue;
                    const float wzy = wz * (dy ? fh_[v] : (1.f - fh_[v]));
                    const int rowbase = (cd * H_ + ch) * W_;
#pragma unroll
                    for (int dx = 0; dx < 2; ++dx) {
                        const int cw = w0_[v] + dx;
                        if ((unsigned)cw >= (unsigned)W_) continue;
                        const float wt = wzy * (dx ? fw_[v] : (1.f - fw_[v]));
                        const int j = 3 * (rowbase + cw);
                        acc[v][0] += wt * __half2float(hp[j]);
                        acc[v][1] += wt * __half2float(hp[j + 1]);
                        acc[v][2] += wt * __half2float(hp[j + 2]);
                    }
                }
            }
        }
        aA0 = acc[0][0]; aA1 = acc[0][1]; aA2 = acc[0][2];
        aB0 = acc[1][0]; aB1 = acc[1][1]; aB2 = acc[1][2];
    }

    const float oA0 = A01.x + aA0, oA1 = A01.y + aA1, oA2 = M.x + aA2;
    const float oB0 = M.y + aB0,  oB1 = B12.x + aB1, oB2 = B12.y + aB2;

    if (PLANAR_OUT) {
        float* out = (float*)out_;
        const int idx = (d * H_ + h) * W_ + wA;    // even -> 8B aligned
        *(float2*)(out + idx)          = make_float2(oA0, oB0);
        *(float2*)(out + NV + idx)     = make_float2(oA1, oB1);
        *(float2*)(out + 2 * NV + idx) = make_float2(oA2, oB2);
    } else {
        U3 o;
        o.a = pk(oA0, oA1);
        o.b = pk(oA2, oB0);
        o.c = pk(oB1, oB2);
        *(U3*)((u32*)out_ + 3 * (size_t)pairIdx) = o;
    }
}

extern "C" void kernel_launch(void* const* d_in, const int* in_sizes, int n_in,
                              void* d_out, int out_size, void* d_ws, size_t ws_size,
                              hipStream_t stream) {
    const float* svf = (const float*)d_in[0];
    float* outp = (float*)d_out;           // final planar fp32 output
    u32* X0 = (u32*)d_ws;                  // fp16 scratch A
    u32* X1 = (u32*)d_out;                 // fp16 scratch B in d_out until last pass

    scale_k<<<NV / 4 / 256, 256, 0, stream>>>(svf, X0);

    dim3 blk(56, 8, 1);                    // 448 threads = 7 waves
    dim3 grd(2, H_ / 8, D_);               // (2, 24, 160)

    compose_k<0><<<grd, blk, 0, stream>>>(X0, X1);
    compose_k<0><<<grd, blk, 0, stream>>>(X1, X0);
    compose_k<0><<<grd, blk, 0, stream>>>(X0, X1);
    compose_k<0><<<grd, blk, 0, stream>>>(X1, X0);
    compose_k<0><<<grd, blk, 0, stream>>>(X0, X1);
    compose_k<0><<<grd, blk, 0, stream>>>(X1, X0);
    compose_k<1><<<grd, blk, 0, stream>>>(X0, outp);
}

// Round 9
// 297.155 us; speedup vs baseline: 1.2127x; 1.2127x over previous
//
#include <hip/hip_runtime.h>
#include <hip/hip_fp16.h>

// Integration_block: scaling-and-squaring SVF integration.
// flow = SVF * 2^-7; 7x: flow = flow + trilerp(flow, p + flow), zeros padding.
// Shape (1, 3, 160, 192, 224) fp32 planar in/out.
//
// Intermediates: fp16, PADDED 8 B/voxel (x,y,z,pad halves). vs R7's tight 6 B:
// +33% bytes but zero funnel-shift extraction VALU, and every access is
// naturally aligned: own-load dwordx2, gather window = one dwordx4 covering
// both w-corners exactly, store dwordx2. R8's counters showed FETCH ~30 MB
// (L3 retains the ping-pong) -> bytes are not binding; VALU/latency are.

#define D_ 160
#define H_ 192
#define W_ 224
static constexpr int NV = D_ * H_ * W_;   // 6,881,280
static constexpr float S_ = 0.0078125f;   // 2^-7
typedef unsigned int u32;

struct __attribute__((packed, aligned(8))) U4 { u32 a, b, c, d; };
struct __attribute__((packed, aligned(8))) U2 { u32 a, b; };

__device__ __forceinline__ float2 h2f(u32 h) {
    __half2 x = *(__half2*)&h;
    return __half22float2(x);
}
__device__ __forceinline__ u32 pk(float a, float b) {
    __half2 h = __floats2half2_rn(a, b);
    return *(u32*)&h;
}
__device__ __forceinline__ float h1f(u32 bits16) {
    __half_raw r; r.x = (unsigned short)bits16;
    return __half2float(__half(r));
}

// planar fp32 SVF -> padded fp16 interleaved (2 u32/voxel), scale folded.
__global__ __launch_bounds__(256) void scale_k(const float* __restrict__ svf,
                                               u32* __restrict__ out) {
    const int i = blockIdx.x * 256 + threadIdx.x;   // NV/4 ids
    float4 a = ((const float4*)svf)[i];             // c0 plane (d-disp)
    float4 b = ((const float4*)(svf + NV))[i];      // c1 plane (h-disp)
    float4 c = ((const float4*)(svf + 2 * NV))[i];  // c2 plane (w-disp)
    u32* o = out + 8 * (size_t)i;
    o[0] = pk(a.x * S_, b.x * S_);  o[1] = pk(c.x * S_, 0.f);
    o[2] = pk(a.y * S_, b.y * S_);  o[3] = pk(c.y * S_, 0.f);
    o[4] = pk(a.z * S_, b.z * S_);  o[5] = pk(c.z * S_, 0.f);
    o[6] = pk(a.w * S_, b.w * S_);  o[7] = pk(c.w * S_, 0.f);
}

template <int PLANAR_OUT>
__global__ __launch_bounds__(256) void compose_k(const u32* __restrict__ in,
                                                 void* __restrict__ out_) {
    const int w = blockIdx.x * 32 + threadIdx.x;   // 224/32 = 7
    const int h = blockIdx.y * 4 + threadIdx.y;    // 192/4  = 48
    const int d = blockIdx.z * 2 + threadIdx.z;    // 160/2  = 80
    const int idx = (d * H_ + h) * W_ + w;

    const U2 uo = *(const U2*)(in + 2 * (size_t)idx);
    const float2 f01 = h2f(uo.a);
    const float f0 = f01.x;
    const float f1 = f01.y;
    const float f2 = h1f(uo.b & 0xffffu);

    const float pd = (float)d + f0;
    const float ph = (float)h + f1;
    const float pw = (float)w + f2;
    const float d0f = floorf(pd), h0f = floorf(ph), w0f = floorf(pw);
    const int d0 = (int)d0f, h0 = (int)h0f, w0 = (int)w0f;
    const float fd = pd - d0f, fh = ph - h0f, fw = pw - w0f;

    float acc0, acc1, acc2;

    const bool interior = ((unsigned)d0 <= (unsigned)(D_ - 2)) &
                          ((unsigned)h0 <= (unsigned)(H_ - 2)) &
                          ((unsigned)w0 <= (unsigned)(W_ - 2));

    if (interior) {
        const int j00 = (d0 * H_ + h0) * W_ + w0;
        const int j01 = j00 + W_;
        const int j10 = j00 + H_ * W_;
        const int j11 = j10 + W_;
        // 4 aligned 16B windows, each = both w-corners of one (d,h) row
        const U4 u0 = *(const U4*)(in + 2 * (size_t)j00);
        const U4 u1 = *(const U4*)(in + 2 * (size_t)j01);
        const U4 u2 = *(const U4*)(in + 2 * (size_t)j10);
        const U4 u3 = *(const U4*)(in + 2 * (size_t)j11);

        const float ww1 = fw, ww0 = 1.f - fw;
        const float wh1 = fh, wh0 = 1.f - fh;
        const float wd1 = fd, wd0 = 1.f - fd;
        const float c00 = wd0 * wh0, c01 = wd0 * wh1;
        const float c10 = wd1 * wh0, c11 = wd1 * wh1;

        // window k: corner0 = (h2f(a), z=b.lo), corner1 = (h2f(c), z=d.lo)
        {
            const float2 q0 = h2f(u0.a), q1 = h2f(u0.c);
            const float z0 = h1f(u0.b & 0xffffu), z1 = h1f(u0.d & 0xffffu);
            acc0 = c00 * (ww0 * q0.x + ww1 * q1.x);
            acc1 = c00 * (ww0 * q0.y + ww1 * q1.y);
            acc2 = c00 * (ww0 * z0 + ww1 * z1);
        }
        {
            const float2 q0 = h2f(u1.a), q1 = h2f(u1.c);
            const float z0 = h1f(u1.b & 0xffffu), z1 = h1f(u1.d & 0xffffu);
            acc0 += c01 * (ww0 * q0.x + ww1 * q1.x);
            acc1 += c01 * (ww0 * q0.y + ww1 * q1.y);
            acc2 += c01 * (ww0 * z0 + ww1 * z1);
        }
        {
            const float2 q0 = h2f(u2.a), q1 = h2f(u2.c);
            const float z0 = h1f(u2.b & 0xffffu), z1 = h1f(u2.d & 0xffffu);
            acc0 += c10 * (ww0 * q0.x + ww1 * q1.x);
            acc1 += c10 * (ww0 * q0.y + ww1 * q1.y);
            acc2 += c10 * (ww0 * z0 + ww1 * z1);
        }
        {
            const float2 q0 = h2f(u3.a), q1 = h2f(u3.c);
            const float z0 = h1f(u3.b & 0xffffu), z1 = h1f(u3.d & 0xffffu);
            acc0 += c11 * (ww0 * q0.x + ww1 * q1.x);
            acc1 += c11 * (ww0 * q0.y + ww1 * q1.y);
            acc2 += c11 * (ww0 * z0 + ww1 * z1);
        }
    } else {
        // boundary: per-corner bounds-checked gather (zeros padding)
        acc0 = acc1 = acc2 = 0.f;
        const __half* hp = (const __half*)in;
#pragma unroll
        for (int dz = 0; dz < 2; ++dz) {
            const int cd = d0 + dz;
            if ((unsigned)cd >= (unsigned)D_) continue;
            const float wz = dz ? fd : (1.f - fd);
#pragma unroll
            for (int dy = 0; dy < 2; ++dy) {
                const int ch = h0 + dy;
                if ((unsigned)ch >= (unsigned)H_) continue;
                const float wzy = wz * (dy ? fh : (1.f - fh));
                const int rowbase = (cd * H_ + ch) * W_;
#pragma unroll
                for (int dx = 0; dx < 2; ++dx) {
                    const int cw = w0 + dx;
                    if ((unsigned)cw >= (unsigned)W_) continue;
                    const float wt = wzy * (dx ? fw : (1.f - fw));
                    const int j = 4 * (rowbase + cw);
                    acc0 += wt * __half2float(hp[j]);
                    acc1 += wt * __half2float(hp[j + 1]);
                    acc2 += wt * __half2float(hp[j + 2]);
                }
            }
        }
    }

    const float o0 = f0 + acc0;
    const float o1 = f1 + acc1;
    const float o2 = f2 + acc2;
    if (PLANAR_OUT) {
        float* out = (float*)out_;
        out[idx]          = o0;
        out[NV + idx]     = o1;
        out[2 * NV + idx] = o2;
    } else {
        U2 o;
        o.a = pk(o0, o1);
        o.b = pk(o2, 0.f);
        *(U2*)((u32*)out_ + 2 * (size_t)idx) = o;
    }
}

extern "C" void kernel_launch(void* const* d_in, const int* in_sizes, int n_in,
                              void* d_out, int out_size, void* d_ws, size_t ws_size,
                              hipStream_t stream) {
    const float* svf = (const float*)d_in[0];
    float* outp = (float*)d_out;           // final planar fp32 output
    u32* X0 = (u32*)d_ws;                  // padded fp16 scratch A (55 MB)
    u32* X1 = (u32*)d_out;                 // padded fp16 scratch B in d_out (82.6 MB avail)

    scale_k<<<NV / 4 / 256, 256, 0, stream>>>(svf, X0);

    dim3 blk(32, 4, 2);
    dim3 grd(W_ / 32, H_ / 4, D_ / 2);     // (7, 48, 80)

    compose_k<0><<<grd, blk, 0, stream>>>(X0, X1);
    compose_k<0><<<grd, blk, 0, stream>>>(X1, X0);
    compose_k<0><<<grd, blk, 0, stream>>>(X0, X1);
    compose_k<0><<<grd, blk, 0, stream>>>(X1, X0);
    compose_k<0><<<grd, blk, 0, stream>>>(X0, X1);
    compose_k<0><<<grd, blk, 0, stream>>>(X1, X0);
    compose_k<1><<<grd, blk, 0, stream>>>(X0, outp);
}